// Round 7
// baseline (271.047 us; speedup 1.0000x reference)
//
#include <hip/hip_runtime.h>
#include <hip/hip_bf16.h>

#define NE 100
#define NB 4096
#define ND 256
#define NF 32
#define NH 16
#define NL 8
#define BT 256   // batch rows per block

typedef float f32x4 __attribute__((ext_vector_type(4)));
typedef float f32x2 __attribute__((ext_vector_type(2)));

__device__ __forceinline__ float sigf(float a) {
    return __builtin_amdgcn_rcpf(1.0f + __expf(-a));
}

// ---------------- phase 1: per-row MLP chain -> d1[32] to workspace ----------------
__global__ __launch_bounds__(256)
void ae_phase1(const float* __restrict__ x,
               const int* __restrict__ idx,
               const float* __restrict__ We0, const float* __restrict__ be0,
               const float* __restrict__ We1, const float* __restrict__ be1,
               const float* __restrict__ Wl,  const float* __restrict__ bl,
               const float* __restrict__ Wd0, const float* __restrict__ bd0,
               const float* __restrict__ Wd1, const float* __restrict__ bd1,
               float* __restrict__ d1g)
{
    __shared__ float s_We0[NF * NH];
    __shared__ float s_We1[NH * NL];
    __shared__ float s_Wl [NL * NL];
    __shared__ float s_Wd0[NL * NH];
    __shared__ float s_Wd1[NH * NF];
    __shared__ float s_be0[NH], s_be1[NL], s_bl[NL], s_bd0[NH], s_bd1[NF];
    __shared__ int   s_idx[NF];

    const int tid = threadIdx.x;
    const int e   = blockIdx.y;
    const int b0  = blockIdx.x * BT;

    {
        const float* We0e = We0 + e * (NF * NH);
        const float* Wd1e = Wd1 + e * (NH * NF);
        for (int i = tid; i < NF * NH; i += 256) { s_We0[i] = We0e[i]; s_Wd1[i] = Wd1e[i]; }
        if (tid < NH * NL) { s_We1[tid] = We1[e * NH * NL + tid];
                             s_Wd0[tid] = Wd0[e * NL * NH + tid]; }
        if (tid < NL * NL) { s_Wl[tid]  = Wl [e * NL * NL + tid]; }
        if (tid < NF)      { s_idx[tid] = idx[e * NF + tid];
                             s_bd1[tid] = bd1[e * NF + tid]; }
        if (tid < NH)      { s_be0[tid] = be0[e * NH + tid];
                             s_bd0[tid] = bd0[e * NH + tid]; }
        if (tid < NL)      { s_be1[tid] = be1[e * NL + tid];
                             s_bl [tid] = bl [e * NL + tid]; }
    }
    __syncthreads();

    const float* xrow = x + (long)(b0 + tid) * ND;

    float xg[NF];
    #pragma unroll
    for (int f = 0; f < NF; ++f) xg[f] = xrow[s_idx[f]];

    float h0[NH];
    #pragma unroll
    for (int h = 0; h < NH; ++h) h0[h] = s_be0[h];
    #pragma unroll
    for (int f = 0; f < NF; ++f) {
        #pragma unroll
        for (int h = 0; h < NH; ++h)
            h0[h] = fmaf(xg[f], s_We0[f * NH + h], h0[h]);
    }
    // no ReLU on h0

    float h1[NL];
    #pragma unroll
    for (int l = 0; l < NL; ++l) h1[l] = s_be1[l];
    #pragma unroll
    for (int h = 0; h < NH; ++h) {
        #pragma unroll
        for (int l = 0; l < NL; ++l)
            h1[l] = fmaf(h0[h], s_We1[h * NL + l], h1[l]);
    }
    #pragma unroll
    for (int l = 0; l < NL; ++l) h1[l] = fmaxf(h1[l], 0.0f);

    float zz[NL];
    #pragma unroll
    for (int m = 0; m < NL; ++m) zz[m] = s_bl[m];
    #pragma unroll
    for (int l = 0; l < NL; ++l) {
        #pragma unroll
        for (int m = 0; m < NL; ++m)
            zz[m] = fmaf(h1[l], s_Wl[l * NL + m], zz[m]);
    }
    #pragma unroll
    for (int m = 0; m < NL; ++m) zz[m] = fmaxf(zz[m], 0.0f);

    float d0[NH];
    #pragma unroll
    for (int h = 0; h < NH; ++h) d0[h] = s_bd0[h];
    #pragma unroll
    for (int l = 0; l < NL; ++l) {
        #pragma unroll
        for (int h = 0; h < NH; ++h)
            d0[h] = fmaf(zz[l], s_Wd0[l * NH + h], d0[h]);
    }
    // no ReLU on d0

    float d1[NF];
    #pragma unroll
    for (int f = 0; f < NF; ++f) d1[f] = s_bd1[f];
    #pragma unroll
    for (int h = 0; h < NH; ++h) {
        #pragma unroll
        for (int f = 0; f < NF; ++f)
            d1[f] = fmaf(d0[h], s_Wd1[h * NF + f], d1[f]);
    }

    float* wrow = d1g + (long)((long)e * NB + b0 + tid) * NF;
    #pragma unroll
    for (int q = 0; q < 8; ++q) {
        f32x4 v;
        v.x = fmaxf(d1[4*q+0], 0.0f);
        v.y = fmaxf(d1[4*q+1], 0.0f);
        v.z = fmaxf(d1[4*q+2], 0.0f);
        v.w = fmaxf(d1[4*q+3], 0.0f);
        *reinterpret_cast<f32x4*>(wrow + 4*q) = v;
    }
}

// ---------------- phase 2: [BT x 32] @ [32 x 256] + sigmoid, pk-fp32 ----------------
// Wave w owns rows [64w,64w+64); lane l owns cols [4l,4l+4).
// d1 row reads are wave-uniform (s_load on SMEM pipe); Wo slab in 128 VGPRs;
// f32x2 math -> v_pk_fma_f32 (2 fp32 FMA/lane/cyc).
__global__ __launch_bounds__(256, 3)
void ae_phase2(const float* __restrict__ d1g,
               const float* __restrict__ Wo, const float* __restrict__ bo,
               float* __restrict__ out)
{
    const int tid = threadIdx.x;
    const int e   = blockIdx.y;
    const int b0  = blockIdx.x * BT;
    const int w   = tid >> 6;
    const int l   = tid & 63;
    const int c0  = l * 4;

    const float* Woe = Wo + (long)e * NF * ND;
    f32x2 wo01[NF], wo23[NF];
    #pragma unroll
    for (int k = 0; k < NF; ++k) {
        f32x4 v = *reinterpret_cast<const f32x4*>(Woe + k * ND + c0);  // coalesced dwordx4
        wo01[k] = f32x2{v.x, v.y};
        wo23[k] = f32x2{v.z, v.w};
    }
    const f32x4 bo4 = *reinterpret_cast<const f32x4*>(bo + e * ND + c0);
    const f32x2 b01 = {bo4.x, bo4.y};
    const f32x2 b23 = {bo4.z, bo4.w};

    const int r0 = w * 64;
    const float* drow = d1g + (long)((long)e * NB + b0 + r0) * NF;   // uniform across wave
    float* obase = out + ((long)e * NB + b0 + r0) * ND + c0;

    for (int r = 0; r < 64; ++r) {
        const float* d = drow + r * NF;   // wave-uniform address -> s_load
        f32x2 a01 = b01, a23 = b23;
        #pragma unroll
        for (int f = 0; f < NF; ++f) {
            const float s = d[f];
            const f32x2 s2 = {s, s};
            a01 = s2 * wo01[f] + a01;     // v_pk_fma_f32
            a23 = s2 * wo23[f] + a23;
        }
        f32x4 o;
        o.x = sigf(a01.x);
        o.y = sigf(a01.y);
        o.z = sigf(a23.x);
        o.w = sigf(a23.y);
        *reinterpret_cast<f32x4*>(obase + (long)r * ND) = o;   // plain store (L2 elasticity)
    }
}

// ---------------- fallback: round-5 fused single kernel (151.7 us) ----------------
__global__ __launch_bounds__(256, 3)
void bagae_fused(const float* __restrict__ x,
                 const int* __restrict__ idx,
                 const float* __restrict__ We0, const float* __restrict__ be0,
                 const float* __restrict__ We1, const float* __restrict__ be1,
                 const float* __restrict__ Wl,  const float* __restrict__ bl,
                 const float* __restrict__ Wd0, const float* __restrict__ bd0,
                 const float* __restrict__ Wd1, const float* __restrict__ bd1,
                 const float* __restrict__ Wo,  const float* __restrict__ bo,
                 float* __restrict__ out)
{
    __shared__ float s_We0[NF * NH];
    __shared__ float s_We1[NH * NL];
    __shared__ float s_Wl [NL * NL];
    __shared__ float s_Wd0[NL * NH];
    __shared__ float s_Wd1[NH * NF];
    __shared__ float s_be0[NH], s_be1[NL], s_bl[NL], s_bd0[NH], s_bd1[NF];
    __shared__ int   s_idx[NF];
    __shared__ float s_d1[BT][36];

    const int tid = threadIdx.x;
    const int e   = blockIdx.y;
    const int b0  = blockIdx.x * BT;

    {
        const float* We0e = We0 + e * (NF * NH);
        const float* Wd1e = Wd1 + e * (NH * NF);
        for (int i = tid; i < NF * NH; i += 256) { s_We0[i] = We0e[i]; s_Wd1[i] = Wd1e[i]; }
        if (tid < NH * NL) { s_We1[tid] = We1[e * NH * NL + tid];
                             s_Wd0[tid] = Wd0[e * NL * NH + tid]; }
        if (tid < NL * NL) { s_Wl[tid]  = Wl [e * NL * NL + tid]; }
        if (tid < NF)      { s_idx[tid] = idx[e * NF + tid];
                             s_bd1[tid] = bd1[e * NF + tid]; }
        if (tid < NH)      { s_be0[tid] = be0[e * NH + tid];
                             s_bd0[tid] = bd0[e * NH + tid]; }
        if (tid < NL)      { s_be1[tid] = be1[e * NL + tid];
                             s_bl [tid] = bl [e * NL + tid]; }
    }
    __syncthreads();

    {
        const float* xrow = x + (long)(b0 + tid) * ND;
        float xg[NF];
        #pragma unroll
        for (int f = 0; f < NF; ++f) xg[f] = xrow[s_idx[f]];
        float h0[NH];
        #pragma unroll
        for (int h = 0; h < NH; ++h) h0[h] = s_be0[h];
        #pragma unroll
        for (int f = 0; f < NF; ++f)
            #pragma unroll
            for (int h = 0; h < NH; ++h)
                h0[h] = fmaf(xg[f], s_We0[f * NH + h], h0[h]);
        float h1[NL];
        #pragma unroll
        for (int l = 0; l < NL; ++l) h1[l] = s_be1[l];
        #pragma unroll
        for (int h = 0; h < NH; ++h)
            #pragma unroll
            for (int l = 0; l < NL; ++l)
                h1[l] = fmaf(h0[h], s_We1[h * NL + l], h1[l]);
        #pragma unroll
        for (int l = 0; l < NL; ++l) h1[l] = fmaxf(h1[l], 0.0f);
        float zz[NL];
        #pragma unroll
        for (int m = 0; m < NL; ++m) zz[m] = s_bl[m];
        #pragma unroll
        for (int l = 0; l < NL; ++l)
            #pragma unroll
            for (int m = 0; m < NL; ++m)
                zz[m] = fmaf(h1[l], s_Wl[l * NL + m], zz[m]);
        #pragma unroll
        for (int m = 0; m < NL; ++m) zz[m] = fmaxf(zz[m], 0.0f);
        float d0[NH];
        #pragma unroll
        for (int h = 0; h < NH; ++h) d0[h] = s_bd0[h];
        #pragma unroll
        for (int l = 0; l < NL; ++l)
            #pragma unroll
            for (int h = 0; h < NH; ++h)
                d0[h] = fmaf(zz[l], s_Wd0[l * NH + h], d0[h]);
        float d1[NF];
        #pragma unroll
        for (int f = 0; f < NF; ++f) d1[f] = s_bd1[f];
        #pragma unroll
        for (int h = 0; h < NH; ++h)
            #pragma unroll
            for (int f = 0; f < NF; ++f)
                d1[f] = fmaf(d0[h], s_Wd1[h * NF + f], d1[f]);
        #pragma unroll
        for (int f = 0; f < NF; ++f)
            s_d1[tid][f] = fmaxf(d1[f], 0.0f);
    }
    __syncthreads();

    {
        const int w  = tid >> 6;
        const int l  = tid & 63;
        const int c0 = l * 4;
        const float* Woe = Wo + (long)e * NF * ND;
        f32x4 wo4[NF];
        #pragma unroll
        for (int k = 0; k < NF; ++k)
            wo4[k] = *reinterpret_cast<const f32x4*>(Woe + k * ND + c0);
        const f32x4 bo4 = *reinterpret_cast<const f32x4*>(bo + e * ND + c0);
        const int r0 = w * 64;
        float* obase = out + ((long)e * NB + b0 + r0) * ND + c0;
        for (int r = 0; r < 64; ++r) {
            const f32x4* dr4 = reinterpret_cast<const f32x4*>(s_d1[r0 + r]);
            float a0 = bo4.x, a1 = bo4.y, a2 = bo4.z, a3 = bo4.w;
            #pragma unroll
            for (int q = 0; q < 8; ++q) {
                f32x4 dv = dr4[q];
                a0 = fmaf(dv.x, wo4[4*q+0].x, a0); a1 = fmaf(dv.x, wo4[4*q+0].y, a1);
                a2 = fmaf(dv.x, wo4[4*q+0].z, a2); a3 = fmaf(dv.x, wo4[4*q+0].w, a3);
                a0 = fmaf(dv.y, wo4[4*q+1].x, a0); a1 = fmaf(dv.y, wo4[4*q+1].y, a1);
                a2 = fmaf(dv.y, wo4[4*q+1].z, a2); a3 = fmaf(dv.y, wo4[4*q+1].w, a3);
                a0 = fmaf(dv.z, wo4[4*q+2].x, a0); a1 = fmaf(dv.z, wo4[4*q+2].y, a1);
                a2 = fmaf(dv.z, wo4[4*q+2].z, a2); a3 = fmaf(dv.z, wo4[4*q+2].w, a3);
                a0 = fmaf(dv.w, wo4[4*q+3].x, a0); a1 = fmaf(dv.w, wo4[4*q+3].y, a1);
                a2 = fmaf(dv.w, wo4[4*q+3].z, a2); a3 = fmaf(dv.w, wo4[4*q+3].w, a3);
            }
            f32x4 o;
            o.x = sigf(a0); o.y = sigf(a1); o.z = sigf(a2); o.w = sigf(a3);
            __builtin_nontemporal_store(o, reinterpret_cast<f32x4*>(obase + (long)r * ND));
        }
    }
}

extern "C" void kernel_launch(void* const* d_in, const int* in_sizes, int n_in,
                              void* d_out, int out_size, void* d_ws, size_t ws_size,
                              hipStream_t stream) {
    const float* x   = (const float*)d_in[0];
    const int*   idx = (const int*)  d_in[1];
    const float* We0 = (const float*)d_in[2];
    const float* be0 = (const float*)d_in[3];
    const float* We1 = (const float*)d_in[4];
    const float* be1 = (const float*)d_in[5];
    const float* Wl  = (const float*)d_in[6];
    const float* bl  = (const float*)d_in[7];
    const float* Wd0 = (const float*)d_in[8];
    const float* bd0 = (const float*)d_in[9];
    const float* Wd1 = (const float*)d_in[10];
    const float* bd1 = (const float*)d_in[11];
    const float* Wo  = (const float*)d_in[12];
    const float* bo  = (const float*)d_in[13];
    float* out = (float*)d_out;

    dim3 grid(NB / BT, NE);
    dim3 block(256);

    const size_t need = (size_t)NE * NB * NF * sizeof(float);   // 52.4 MB
    if (ws_size >= need) {
        float* d1g = (float*)d_ws;
        hipLaunchKernelGGL(ae_phase1, grid, block, 0, stream,
                           x, idx, We0, be0, We1, be1, Wl, bl,
                           Wd0, bd0, Wd1, bd1, d1g);
        hipLaunchKernelGGL(ae_phase2, grid, block, 0, stream,
                           d1g, Wo, bo, out);
    } else {
        hipLaunchKernelGGL(bagae_fused, grid, block, 0, stream,
                           x, idx, We0, be0, We1, be1, Wl, bl,
                           Wd0, bd0, Wd1, bd1, Wo, bo, out);
    }
}

// Round 8
// 163.731 us; speedup vs baseline: 1.6554x; 1.6554x over previous
//
#include <hip/hip_runtime.h>
#include <hip/hip_bf16.h>

#define NE 100
#define NB 4096
#define ND 256
#define NF 32
#define NH 16
#define NL 8
#define BT 256   // batch rows per block

typedef float  floatx4 __attribute__((ext_vector_type(4)));
typedef short  short8  __attribute__((ext_vector_type(8)));

__device__ __forceinline__ float sigf(float a) {
    return __builtin_amdgcn_rcpf(1.0f + __expf(-a));
}
__device__ __forceinline__ unsigned short f2bf_rne(float f) {
    unsigned u = __float_as_uint(f);
    unsigned r = u + 0x7FFFu + ((u >> 16) & 1u);
    return (unsigned short)(r >> 16);
}
__device__ __forceinline__ float bf2f(unsigned short h) {
    return __uint_as_float(((unsigned)h) << 16);
}

// Fused: phase1 per-row MLP (VALU) -> bf16 hi/lo fragments in LDS ->
// phase2 [256x32]@[32x256] via mfma_f32_16x16x32_bf16 (3-term hi/lo split).
// Fragment LDS layout (A and B identical construction, so the HW's
// (lanegroup,elem)->k map cancels in the contraction):
//   unit u(tile,kc,i16) = tile*64 + kc*16 + i16   (16B units, 8 bf16 each)
//   lane l of tile t reads unit t*64 + l  -> linear, conflict-free.
__global__ __launch_bounds__(256, 2)
void bagae_mfma(const float* __restrict__ x,
                const int* __restrict__ idx,
                const float* __restrict__ We0, const float* __restrict__ be0,
                const float* __restrict__ We1, const float* __restrict__ be1,
                const float* __restrict__ Wl,  const float* __restrict__ bl,
                const float* __restrict__ Wd0, const float* __restrict__ bd0,
                const float* __restrict__ Wd1, const float* __restrict__ bd1,
                const float* __restrict__ Wo,  const float* __restrict__ bo,
                float* __restrict__ out)
{
    __shared__ short sAhi[BT * NF];   // 16 KB, fragment-ordered d1 (hi)
    __shared__ short sAlo[BT * NF];   // 16 KB (lo residual)
    __shared__ short sBhi[ND * NF];   // 16 KB, fragment-ordered Wo (hi)
    __shared__ short sBlo[ND * NF];   // 16 KB (lo residual)
    __shared__ float s_We0[NF * NH];
    __shared__ float s_We1[NH * NL];
    __shared__ float s_Wl [NL * NL];
    __shared__ float s_Wd0[NL * NH];
    __shared__ float s_Wd1[NH * NF];
    __shared__ float s_be0[NH], s_be1[NL], s_bl[NL], s_bd0[NH], s_bd1[NF];
    __shared__ int   s_idx[NF];

    const int tid = threadIdx.x;
    const int e   = blockIdx.y;
    const int b0  = blockIdx.x * BT;

    // ---- stage small per-estimator weights ----
    {
        const float* We0e = We0 + e * (NF * NH);
        const float* Wd1e = Wd1 + e * (NH * NF);
        for (int i = tid; i < NF * NH; i += 256) { s_We0[i] = We0e[i]; s_Wd1[i] = Wd1e[i]; }
        if (tid < NH * NL) { s_We1[tid] = We1[e * NH * NL + tid];
                             s_Wd0[tid] = Wd0[e * NL * NH + tid]; }
        if (tid < NL * NL) { s_Wl[tid]  = Wl [e * NL * NL + tid]; }
        if (tid < NF)      { s_idx[tid] = idx[e * NF + tid];
                             s_bd1[tid] = bd1[e * NF + tid]; }
        if (tid < NH)      { s_be0[tid] = be0[e * NH + tid];
                             s_bd0[tid] = bd0[e * NH + tid]; }
        if (tid < NL)      { s_be1[tid] = be1[e * NL + tid];
                             s_bl [tid] = bl [e * NL + tid]; }
    }

    // ---- stage B = Wo_e column tid as hi/lo bf16 fragments ----
    {
        const float* Woe = Wo + (long)e * NF * ND;
        float wcol[NF];
        #pragma unroll
        for (int k = 0; k < NF; ++k) wcol[k] = Woe[k * ND + tid];   // coalesced across lanes
        const int ct = tid >> 4, c16 = tid & 15;
        #pragma unroll
        for (int kc = 0; kc < 4; ++kc) {
            short8 hi, lo;
            #pragma unroll
            for (int j = 0; j < 8; ++j) {
                float v = wcol[kc * 8 + j];
                unsigned short h = f2bf_rne(v);
                hi[j] = (short)h;
                lo[j] = (short)f2bf_rne(v - bf2f(h));
            }
            const int u = (ct * 4 + kc) * 16 + c16;
            *reinterpret_cast<short8*>(&sBhi[u * 8]) = hi;
            *reinterpret_cast<short8*>(&sBlo[u * 8]) = lo;
        }
    }
    __syncthreads();

    // ---- phase 1: per-row MLP chain -> d1[32] (relu) -> A fragments ----
    {
        const float* xrow = x + (long)(b0 + tid) * ND;

        float xg[NF];
        #pragma unroll
        for (int f = 0; f < NF; ++f) xg[f] = xrow[s_idx[f]];

        float h0[NH];
        #pragma unroll
        for (int h = 0; h < NH; ++h) h0[h] = s_be0[h];
        #pragma unroll
        for (int f = 0; f < NF; ++f) {
            #pragma unroll
            for (int h = 0; h < NH; ++h)
                h0[h] = fmaf(xg[f], s_We0[f * NH + h], h0[h]);
        }
        // no ReLU on h0

        float h1[NL];
        #pragma unroll
        for (int l = 0; l < NL; ++l) h1[l] = s_be1[l];
        #pragma unroll
        for (int h = 0; h < NH; ++h) {
            #pragma unroll
            for (int l = 0; l < NL; ++l)
                h1[l] = fmaf(h0[h], s_We1[h * NL + l], h1[l]);
        }
        #pragma unroll
        for (int l = 0; l < NL; ++l) h1[l] = fmaxf(h1[l], 0.0f);

        float zz[NL];
        #pragma unroll
        for (int m = 0; m < NL; ++m) zz[m] = s_bl[m];
        #pragma unroll
        for (int l = 0; l < NL; ++l) {
            #pragma unroll
            for (int m = 0; m < NL; ++m)
                zz[m] = fmaf(h1[l], s_Wl[l * NL + m], zz[m]);
        }
        #pragma unroll
        for (int m = 0; m < NL; ++m) zz[m] = fmaxf(zz[m], 0.0f);

        float d0[NH];
        #pragma unroll
        for (int h = 0; h < NH; ++h) d0[h] = s_bd0[h];
        #pragma unroll
        for (int l = 0; l < NL; ++l) {
            #pragma unroll
            for (int h = 0; h < NH; ++h)
                d0[h] = fmaf(zz[l], s_Wd0[l * NH + h], d0[h]);
        }
        // no ReLU on d0

        float d1[NF];
        #pragma unroll
        for (int f = 0; f < NF; ++f) d1[f] = s_bd1[f];
        #pragma unroll
        for (int h = 0; h < NH; ++h) {
            #pragma unroll
            for (int f = 0; f < NF; ++f)
                d1[f] = fmaf(d0[h], s_Wd1[h * NF + f], d1[f]);
        }

        const int t = tid >> 4, r16 = tid & 15;
        #pragma unroll
        for (int kc = 0; kc < 4; ++kc) {
            short8 hi, lo;
            #pragma unroll
            for (int j = 0; j < 8; ++j) {
                float v = fmaxf(d1[kc * 8 + j], 0.0f);   // relu on d1
                unsigned short h = f2bf_rne(v);
                hi[j] = (short)h;
                lo[j] = (short)f2bf_rne(v - bf2f(h));
            }
            const int u = (t * 4 + kc) * 16 + r16;
            *reinterpret_cast<short8*>(&sAhi[u * 8]) = hi;
            *reinterpret_cast<short8*>(&sAlo[u * 8]) = lo;
        }
    }
    __syncthreads();

    // ---- phase 2: MFMA GEMM + sigmoid + NT stores ----
    {
        const int w   = tid >> 6;     // wave id: row-tiles [4w, 4w+4)
        const int l   = tid & 63;
        const int sub = l >> 4;       // D rows sub*4 .. sub*4+3
        const int c16 = l & 15;       // D col within tile

        short8 bhi[16], blo[16];
        #pragma unroll
        for (int ct = 0; ct < 16; ++ct) {
            bhi[ct] = *reinterpret_cast<const short8*>(&sBhi[(ct * 64 + l) * 8]);
            blo[ct] = *reinterpret_cast<const short8*>(&sBlo[(ct * 64 + l) * 8]);
        }
        float bias[16];
        #pragma unroll
        for (int ct = 0; ct < 16; ++ct)
            bias[ct] = bo[e * ND + ct * 16 + c16];

        #pragma unroll
        for (int i = 0; i < 4; ++i) {
            const int rt = w * 4 + i;
            const short8 ahi = *reinterpret_cast<const short8*>(&sAhi[(rt * 64 + l) * 8]);
            const short8 alo = *reinterpret_cast<const short8*>(&sAlo[(rt * 64 + l) * 8]);

            const long rowbase = (long)e * NB + (b0 + rt * 16 + sub * 4);
            float* po = out + rowbase * ND + c16;

            #pragma unroll
            for (int ct = 0; ct < 16; ++ct) {
                floatx4 acc = {bias[ct], bias[ct], bias[ct], bias[ct]};
                acc = __builtin_amdgcn_mfma_f32_16x16x32_bf16(ahi, bhi[ct], acc, 0, 0, 0);
                acc = __builtin_amdgcn_mfma_f32_16x16x32_bf16(ahi, blo[ct], acc, 0, 0, 0);
                acc = __builtin_amdgcn_mfma_f32_16x16x32_bf16(alo, bhi[ct], acc, 0, 0, 0);
                #pragma unroll
                for (int r = 0; r < 4; ++r)
                    __builtin_nontemporal_store(sigf(acc[r]), po + (long)r * ND + ct * 16);
            }
        }
    }
}

extern "C" void kernel_launch(void* const* d_in, const int* in_sizes, int n_in,
                              void* d_out, int out_size, void* d_ws, size_t ws_size,
                              hipStream_t stream) {
    const float* x   = (const float*)d_in[0];
    const int*   idx = (const int*)  d_in[1];
    const float* We0 = (const float*)d_in[2];
    const float* be0 = (const float*)d_in[3];
    const float* We1 = (const float*)d_in[4];
    const float* be1 = (const float*)d_in[5];
    const float* Wl  = (const float*)d_in[6];
    const float* bl  = (const float*)d_in[7];
    const float* Wd0 = (const float*)d_in[8];
    const float* bd0 = (const float*)d_in[9];
    const float* Wd1 = (const float*)d_in[10];
    const float* bd1 = (const float*)d_in[11];
    const float* Wo  = (const float*)d_in[12];
    const float* bo  = (const float*)d_in[13];
    float* out = (float*)d_out;

    dim3 grid(NB / BT, NE);
    dim3 block(256);
    hipLaunchKernelGGL(bagae_mfma, grid, block, 0, stream,
                       x, idx, We0, be0, We1, be1, Wl, bl,
                       Wd0, bd0, Wd1, bd1, Wo, bo, out);
}